// Round 6
// baseline (853.374 us; speedup 1.0000x reference)
//
#include <hip/hip_runtime.h>
#include <stdint.h>

// GCN, DIM=1. Three-tier strategy.
// FULL: 2-pass edge sort: pass1 bins by (8192-node dst-bucket x src-half)
//       [246 bins, u32 rec = dstloc13<<19 | src&0x7FFFF]; pass2 sorts each bin
//       by 4096-src window (LDS-staged counting sort, block-local). Per layer,
//       aggregation streams edges in window order, stages each 16KB h-window
//       into LDS (prefetch-into-regs), and does only LDS ops per edge: no
//       random global accesses in the layer loop at all.
// TIER2 (less workspace): gather path on pass1 output (~R4 behavior).
// TIER3: global-atomic scatter.

static constexpr int NGRAPHS  = 256;
static constexpr int TB       = 256;
static constexpr int TB_P     = 512;    // place block
static constexpr int PGRID    = 256;    // place grid (1 block/CU)
static constexpr int TB2      = 1024;   // window_sort block
static constexpr int TB_A     = 1024;   // agg block
static constexpr int DSTB_LOG = 13;
static constexpr int DSTB     = 1 << DSTB_LOG;   // 8192 dst nodes per bucket
static constexpr int MAXB     = 256;             // max bins (2*nbd <= 256)
static constexpr int WLOG     = 12;
static constexpr int WIN      = 1 << WLOG;       // 4096 srcs per window
static constexpr int NW       = 128;             // windows per src-half (2^19/4096)
static constexpr int TILE2    = 4096;            // pass2 staging tile

// ---------------- common ----------------

__global__ void node_init(const float4* __restrict__ x,
                          const float* __restrict__ W0n,
                          const float* __restrict__ W0s,
                          float* __restrict__ xw0,
                          float* __restrict__ s0,
                          int n_nodes) {
    int n = blockIdx.x * blockDim.x + threadIdx.x;
    if (n >= n_nodes) return;
    float4 a = x[2 * n];
    float4 b = x[2 * n + 1];
    float xn = a.x * W0n[0] + a.y * W0n[1] + a.z * W0n[2] + a.w * W0n[3] +
               b.x * W0n[4] + b.y * W0n[5] + b.z * W0n[6] + b.w * W0n[7];
    float xs = a.x * W0s[0] + a.y * W0s[1] + a.z * W0s[2] + a.w * W0s[3] +
               b.x * W0s[4] + b.y * W0s[5] + b.z * W0s[6] + b.w * W0s[7];
    xw0[n] = xn;
    s0[n] = xs;
}

__global__ void head(const float* __restrict__ hg,
                     const float* __restrict__ fc1_w,
                     const float* __restrict__ fc1_b,
                     const float* __restrict__ out_w,
                     const float* __restrict__ out_b,
                     float* __restrict__ out) {
    int gph = threadIdx.x;
    if (gph >= NGRAPHS) return;
    float hv = hg[gph];
    float o0 = out_b[0], o1 = out_b[1], o2 = out_b[2], o3 = out_b[3];
#pragma unroll
    for (int j = 0; j < 8; ++j) {
        float z = (hv * fc1_w[j] + fc1_b[j]) * 1000.0f;
        float sg = 1.0f / (1.0f + expf(-z));
        o0 += sg * out_w[j * 4 + 0];
        o1 += sg * out_w[j * 4 + 1];
        o2 += sg * out_w[j * 4 + 2];
        o3 += sg * out_w[j * 4 + 3];
    }
    o0 = fmaxf(o0, 0.0f); o1 = fmaxf(o1, 0.0f);
    o2 = fmaxf(o2, 0.0f); o3 = fmaxf(o3, 0.0f);
    float m = fmaxf(fmaxf(o0, o1), fmaxf(o2, o3));
    float s = expf(o0 - m) + expf(o1 - m) + expf(o2 - m) + expf(o3 - m);
    float l = logf(s);
    out[gph * 4 + 0] = o0 - m - l;
    out[gph * 4 + 1] = o1 - m - l;
    out[gph * 4 + 2] = o2 - m - l;
    out[gph * 4 + 3] = o3 - m - l;
}

__device__ __forceinline__ int bin1_of(int d, int s) {
    return ((d >> DSTB_LOG) << 1) | ((unsigned)s >> 19);
}
__device__ __forceinline__ uint32_t rec_of(int d, int s) {
    return ((uint32_t)(d & (DSTB - 1)) << 19) | ((uint32_t)s & 0x7FFFFu);
}

// ---------------- build: count + scan + pass1 ----------------

__global__ void count_bins2(const int* __restrict__ src,
                            const int* __restrict__ dst,
                            int n_edges, int nbins,
                            int* __restrict__ counts) {
    __shared__ int hist[MAXB];
    for (int i = threadIdx.x; i < MAXB; i += blockDim.x) hist[i] = 0;
    __syncthreads();
    const int4* s4 = (const int4*)src;
    const int4* d4 = (const int4*)dst;
    int nq = n_edges >> 2;
    int g = blockIdx.x * blockDim.x + threadIdx.x;
    int stride = gridDim.x * blockDim.x;
    for (int q = g; q < nq; q += stride) {
        int4 d = d4[q]; int4 s = s4[q];
        atomicAdd(&hist[bin1_of(d.x, s.x)], 1);
        atomicAdd(&hist[bin1_of(d.y, s.y)], 1);
        atomicAdd(&hist[bin1_of(d.z, s.z)], 1);
        atomicAdd(&hist[bin1_of(d.w, s.w)], 1);
    }
    if (blockIdx.x == 0) {
        for (int e = (nq << 2) + threadIdx.x; e < n_edges; e += blockDim.x)
            atomicAdd(&hist[bin1_of(dst[e], src[e])], 1);
    }
    __syncthreads();
    for (int i = threadIdx.x; i < nbins; i += blockDim.x)
        if (hist[i]) atomicAdd(&counts[i], hist[i]);
}

__global__ void scan_offsets(const int* __restrict__ counts, int nbins,
                             int* __restrict__ offs, int* __restrict__ cursor) {
    __shared__ int lds[MAXB];
    int i = threadIdx.x;
    int c = (i < nbins) ? counts[i] : 0;
    lds[i] = c;
    __syncthreads();
    for (int off = 1; off < MAXB; off <<= 1) {
        int v = (i >= off) ? lds[i - off] : 0;
        __syncthreads();
        lds[i] += v;
        __syncthreads();
    }
    int excl = lds[i] - c;
    offs[i] = excl;                // for i >= nbins this equals total
    if (i < nbins) cursor[i] = excl;
    if (i == MAXB - 1) offs[MAXB] = lds[MAXB - 1];
}

__global__ void place1(const int* __restrict__ src,
                       const int* __restrict__ dst,
                       int n_edges, int nbins,
                       int* __restrict__ cursor,
                       uint32_t* __restrict__ sorted) {
    __shared__ int hist[MAXB];
    for (int i = threadIdx.x; i < MAXB; i += blockDim.x) hist[i] = 0;
    __syncthreads();

    const int nq = n_edges >> 2;
    const int per = (nq + gridDim.x - 1) / gridDim.x;
    const int b0 = blockIdx.x * per;
    const int b1 = min(b0 + per, nq);
    const bool last = (blockIdx.x == gridDim.x - 1);
    const int tail = nq << 2;

    const int4* s4 = (const int4*)src;
    const int4* d4 = (const int4*)dst;

    // A: chunk histogram
    for (int q = b0 + threadIdx.x; q < b1; q += blockDim.x) {
        int4 d = d4[q]; int4 s = s4[q];
        atomicAdd(&hist[bin1_of(d.x, s.x)], 1);
        atomicAdd(&hist[bin1_of(d.y, s.y)], 1);
        atomicAdd(&hist[bin1_of(d.z, s.z)], 1);
        atomicAdd(&hist[bin1_of(d.w, s.w)], 1);
    }
    if (last) {
        for (int e = tail + threadIdx.x; e < n_edges; e += blockDim.x)
            atomicAdd(&hist[bin1_of(dst[e], src[e])], 1);
    }
    __syncthreads();
    // B: reserve
    for (int b = threadIdx.x; b < nbins; b += blockDim.x) {
        int h = hist[b];
        hist[b] = h ? atomicAdd(&cursor[b], h) : 0;
    }
    __syncthreads();
    // C: place
    for (int q = b0 + threadIdx.x; q < b1; q += blockDim.x) {
        int4 d = d4[q]; int4 s = s4[q];
        int p0 = atomicAdd(&hist[bin1_of(d.x, s.x)], 1);
        int p1 = atomicAdd(&hist[bin1_of(d.y, s.y)], 1);
        int p2 = atomicAdd(&hist[bin1_of(d.z, s.z)], 1);
        int p3 = atomicAdd(&hist[bin1_of(d.w, s.w)], 1);
        sorted[p0] = rec_of(d.x, s.x);
        sorted[p1] = rec_of(d.y, s.y);
        sorted[p2] = rec_of(d.z, s.z);
        sorted[p3] = rec_of(d.w, s.w);
    }
    if (last) {
        for (int e = tail + threadIdx.x; e < n_edges; e += blockDim.x) {
            int pos = atomicAdd(&hist[bin1_of(dst[e], src[e])], 1);
            sorted[pos] = rec_of(dst[e], src[e]);
        }
    }
}

// ---------------- pass2: per-bin window sort (LDS-staged) ----------------

__global__ void window_sort(const uint32_t* __restrict__ s1,
                            const int* __restrict__ offs,
                            uint32_t* __restrict__ s2,
                            int* __restrict__ woffs) {
    __shared__ int whist[NW];
    __shared__ int wcur[NW];
    __shared__ int thist[NW];
    __shared__ int tincl[NW];
    __shared__ int tcur[NW];
    __shared__ uint32_t stg[TILE2];
    __shared__ uint8_t bid[TILE2];
    const int bin = blockIdx.x;
    const int tid = threadIdx.x;
    const int beg = offs[bin], end = offs[bin + 1];

    // pass A: full-bin window histogram
    if (tid < NW) whist[tid] = 0;
    __syncthreads();
    for (int e = beg + tid; e < end; e += TB2)
        atomicAdd(&whist[(s1[e] >> WLOG) & (NW - 1)], 1);
    __syncthreads();
    // exclusive scan whist -> wcur, dump woffs
    if (tid < NW) wcur[tid] = whist[tid];
    __syncthreads();
    for (int off = 1; off < NW; off <<= 1) {
        int v = (tid < NW && tid >= off) ? wcur[tid - off] : 0;
        __syncthreads();
        if (tid < NW) wcur[tid] += v;
        __syncthreads();
    }
    if (tid < NW) {
        int excl = wcur[tid] - whist[tid];
        wcur[tid] = excl;
        woffs[bin * (NW + 1) + tid] = beg + excl;
    }
    if (tid == 0) woffs[bin * (NW + 1) + NW] = end;
    __syncthreads();

    // pass B: staged tiles
    for (int tb = beg; tb < end; tb += TILE2) {
        const int cnt = min(TILE2, end - tb);
        if (tid < NW) thist[tid] = 0;
        __syncthreads();
        uint32_t r[TILE2 / TB2];
        int bn[TILE2 / TB2];
#pragma unroll
        for (int k = 0; k < TILE2 / TB2; ++k) {
            int e = tb + k * TB2 + tid;
            if (e < end) {
                r[k] = s1[e];
                bn[k] = (r[k] >> WLOG) & (NW - 1);
                atomicAdd(&thist[bn[k]], 1);
            } else bn[k] = -1;
        }
        __syncthreads();
        if (tid < NW) tincl[tid] = thist[tid];
        __syncthreads();
        for (int off = 1; off < NW; off <<= 1) {
            int v = (tid < NW && tid >= off) ? tincl[tid - off] : 0;
            __syncthreads();
            if (tid < NW) tincl[tid] += v;
            __syncthreads();
        }
        if (tid < NW) tcur[tid] = tincl[tid] - thist[tid];   // exclusive start
        __syncthreads();
#pragma unroll
        for (int k = 0; k < TILE2 / TB2; ++k) {
            if (bn[k] >= 0) {
                int p = atomicAdd(&tcur[bn[k]], 1);
                stg[p] = r[k];
                bid[p] = (uint8_t)bn[k];
            }
        }
        __syncthreads();
        for (int i = tid; i < cnt; i += TB2) {
            int w = bid[i];
            int es = tincl[w] - thist[w];
            s2[beg + wcur[w] + (i - es)] = stg[i];
        }
        __syncthreads();
        if (tid < NW) wcur[tid] += thist[tid];
        __syncthreads();
    }
}

// ---------------- per-layer aggregation: windowed, all-LDS ----------------

__global__ void window_agg(const uint32_t* __restrict__ s2,
                           const int* __restrict__ woffs,
                           const float* __restrict__ gsrc,   // padded to 2^20 floats
                           float* __restrict__ partial) {
    __shared__ float acc[DSTB];    // 32 KB
    __shared__ float win[WIN];     // 16 KB
    const int bin = blockIdx.x >> 1;
    const int wh = blockIdx.x & 1;
    const int tid = threadIdx.x;
    for (int i = tid; i < DSTB; i += TB_A) acc[i] = 0.0f;
    const unsigned halfBase = ((unsigned)(bin & 1)) << 19;
    const int w0 = wh * (NW / 2), w1 = w0 + NW / 2;
    const int* wo = woffs + bin * (NW + 1);
    // prefetch first window into regs
    float4 nxt = ((const float4*)(gsrc + halfBase + (unsigned)w0 * WIN))[tid];
    for (int w = w0; w < w1; ++w) {
        __syncthreads();                       // acc/win ready
        ((float4*)win)[tid] = nxt;
        __syncthreads();
        if (w + 1 < w1)
            nxt = ((const float4*)(gsrc + halfBase + (unsigned)(w + 1) * WIN))[tid];
        const int es = wo[w], ee = wo[w + 1];
        for (int e = es + tid; e < ee; e += TB_A) {
            uint32_t r = s2[e];
            atomicAdd(&acc[r >> 19], win[r & (WIN - 1)]);
        }
    }
    __syncthreads();
    float* o = partial + (size_t)blockIdx.x * DSTB;
    for (int i = tid; i < DSTB; i += TB_A) o[i] = acc[i];
}

// tier2: plain gather aggregation over pass1 output (one block per bin)
__global__ void plain_agg(const uint32_t* __restrict__ s1,
                          const int* __restrict__ offs,
                          const float* __restrict__ gsrc,
                          float* __restrict__ partial) {
    __shared__ float acc[DSTB];
    const int bin = blockIdx.x;
    const int tid = threadIdx.x;
    for (int i = tid; i < DSTB; i += TB_A) acc[i] = 0.0f;
    __syncthreads();
    const unsigned hb = ((unsigned)(bin & 1)) << 19;
    int e = offs[bin] + tid;
    const int ee = offs[bin + 1];
    for (; e + 3 * TB_A < ee; e += 4 * TB_A) {
        uint32_t r0 = s1[e];
        uint32_t r1 = s1[e + TB_A];
        uint32_t r2 = s1[e + 2 * TB_A];
        uint32_t r3 = s1[e + 3 * TB_A];
        float v0 = gsrc[hb | (r0 & 0x7FFFFu)];
        float v1 = gsrc[hb | (r1 & 0x7FFFFu)];
        float v2 = gsrc[hb | (r2 & 0x7FFFFu)];
        float v3 = gsrc[hb | (r3 & 0x7FFFFu)];
        atomicAdd(&acc[r0 >> 19], v0);
        atomicAdd(&acc[r1 >> 19], v1);
        atomicAdd(&acc[r2 >> 19], v2);
        atomicAdd(&acc[r3 >> 19], v3);
    }
    for (; e < ee; e += TB_A) {
        uint32_t r = s1[e];
        atomicAdd(&acc[r >> 19], gsrc[hb | (r & 0x7FFFFu)]);
    }
    __syncthreads();
    float* o = partial + (size_t)bin * DSTB;
    for (int i = tid; i < DSTB; i += TB_A) o[i] = acc[i];
}

// ---------------- reduce + fused node update ----------------

__global__ void reduce_l0(const float* __restrict__ partial, int nsp,
                          const float* __restrict__ s0,
                          const float* __restrict__ b0,
                          float* __restrict__ h_out, int n_nodes) {
    int k = blockIdx.x;
    int base = k << DSTB_LOG;
    int nloc = min(DSTB, n_nodes - base);
    float bb = b0[0];
    const float* p = partial + (size_t)k * nsp * DSTB;
    for (int i = threadIdx.x; i < nloc; i += blockDim.x) {
        float v = 0.0f;
        for (int j = 0; j < nsp; ++j) v += p[(size_t)j * DSTB + i];
        h_out[base + i] = fmaxf(v + bb + s0[base + i], 0.0f);
    }
}

__global__ void reduce_lk(const float* __restrict__ partial, int nsp,
                          const float* __restrict__ h_in,
                          const float* __restrict__ Wkn,
                          const float* __restrict__ bk,
                          const float* __restrict__ Wks,
                          int li, float* __restrict__ h_out, int n_nodes) {
    int k = blockIdx.x;
    int base = k << DSTB_LOG;
    int nloc = min(DSTB, n_nodes - base);
    float wn = Wkn[li], bb = bk[li], ws = Wks[li];
    const float* p = partial + (size_t)k * nsp * DSTB;
    for (int i = threadIdx.x; i < nloc; i += blockDim.x) {
        float v = 0.0f;
        for (int j = 0; j < nsp; ++j) v += p[(size_t)j * DSTB + i];
        h_out[base + i] = fmaxf(wn * v + bb + ws * h_in[base + i], 0.0f);
    }
}

__global__ void reduce_last(const float* __restrict__ partial, int nsp,
                            const float* __restrict__ h_in,
                            const int* __restrict__ graph_ids,
                            const float* __restrict__ Wkn,
                            const float* __restrict__ bk,
                            const float* __restrict__ Wks,
                            int li, float* __restrict__ hg, int n_nodes) {
    int k = blockIdx.x;
    int base = k << DSTB_LOG;
    int nloc = min(DSTB, n_nodes - base);
    float wn = Wkn[li], bb = bk[li], ws = Wks[li];
    const float* p = partial + (size_t)k * nsp * DSTB;
    for (int i = threadIdx.x; i < DSTB; i += blockDim.x) {  // uniform bound
        float val = 0.0f;
        int g = -1;
        if (i < nloc) {
            float v = 0.0f;
            for (int j = 0; j < nsp; ++j) v += p[(size_t)j * DSTB + i];
            int n = base + i;
            val = fmaxf(wn * v + bb + ws * h_in[n], 0.0f);
            g = graph_ids[n];
        }
        int g0 = __shfl(g, 0);
        unsigned long long same = __ballot(g == g0);
        if (same == ~0ULL) {
            for (int o = 32; o > 0; o >>= 1) val += __shfl_down(val, o);
            if ((threadIdx.x & 63) == 0 && g >= 0) atomicAdd(&hg[g], val);
        } else if (g >= 0) {
            atomicAdd(&hg[g], val);
        }
    }
}

// ---------------- tier3: global-atomic fallback ----------------

__global__ void edge_scatter(const int4* __restrict__ src4,
                             const int4* __restrict__ dst4,
                             const float* __restrict__ val,
                             float* __restrict__ agg, int nquads) {
    int t = blockIdx.x * blockDim.x + threadIdx.x;
    if (t >= nquads) return;
    int4 s = src4[t]; int4 d = dst4[t];
    atomicAdd(&agg[d.x], val[s.x]);
    atomicAdd(&agg[d.y], val[s.y]);
    atomicAdd(&agg[d.z], val[s.z]);
    atomicAdd(&agg[d.w], val[s.w]);
}

__global__ void node_l0(float* __restrict__ agg, const float* __restrict__ s0,
                        const float* __restrict__ b0, float* __restrict__ h, int n_nodes) {
    int n = blockIdx.x * blockDim.x + threadIdx.x;
    if (n >= n_nodes) return;
    h[n] = fmaxf(agg[n] + b0[0] + s0[n], 0.0f);
    agg[n] = 0.0f;
}

__global__ void node_lk(float* __restrict__ agg, float* __restrict__ h,
                        const float* __restrict__ Wkn, const float* __restrict__ bk,
                        const float* __restrict__ Wks, int li, int n_nodes) {
    int n = blockIdx.x * blockDim.x + threadIdx.x;
    if (n >= n_nodes) return;
    float v = Wkn[li] * agg[n] + bk[li] + Wks[li] * h[n];
    h[n] = fmaxf(v, 0.0f);
    agg[n] = 0.0f;
}

__global__ void node_l3_readout(const float* __restrict__ agg, const float* __restrict__ h,
                                const int* __restrict__ graph_ids,
                                const float* __restrict__ Wkn, const float* __restrict__ bk,
                                const float* __restrict__ Wks, float* __restrict__ hg,
                                int n_nodes) {
    int n = blockIdx.x * blockDim.x + threadIdx.x;
    float val = 0.0f;
    int g = -1;
    if (n < n_nodes) {
        val = fmaxf(Wkn[2] * agg[n] + bk[2] + Wks[2] * h[n], 0.0f);
        g = graph_ids[n];
    }
    int g0 = __shfl(g, 0);
    unsigned long long same = __ballot(g == g0);
    if (same == ~0ULL) {
        for (int o = 32; o > 0; o >>= 1) val += __shfl_down(val, o);
        if ((threadIdx.x & 63) == 0 && g >= 0) atomicAdd(&hg[g], val);
    } else if (g >= 0) {
        atomicAdd(&hg[g], val);
    }
}

// ---------------- launch ----------------

extern "C" void kernel_launch(void* const* d_in, const int* in_sizes, int n_in,
                              void* d_out, int out_size, void* d_ws, size_t ws_size,
                              hipStream_t stream) {
    const float* x        = (const float*)d_in[0];
    const int*   src      = (const int*)d_in[1];
    const int*   dst      = (const int*)d_in[2];
    const int*   graphids = (const int*)d_in[3];
    const float* W0n   = (const float*)d_in[5];
    const float* b0    = (const float*)d_in[6];
    const float* W0s   = (const float*)d_in[7];
    const float* Wkn   = (const float*)d_in[8];
    const float* bk    = (const float*)d_in[9];
    const float* Wks   = (const float*)d_in[10];
    const float* fc1_w = (const float*)d_in[11];
    const float* fc1_b = (const float*)d_in[12];
    const float* out_w = (const float*)d_in[13];
    const float* out_b = (const float*)d_in[14];
    float* out = (float*)d_out;

    const int n_nodes = in_sizes[0] / 8;
    const int n_edges = in_sizes[1];
    const int nbd     = (n_nodes + DSTB - 1) >> DSTB_LOG;   // dst buckets
    const int nbins   = 2 * nbd;                            // x src-half
    const int node_blocks = (n_nodes + TB - 1) / TB;

    const size_t E4   = (size_t)n_edges * 4;
    const size_t NBP  = (size_t)(1 << 20) * sizeof(float);  // padded node array (4MB)
    const size_t SMALL = (MAXB + (MAXB + 1) + MAXB + NGRAPHS) * sizeof(int);
    const size_t WOFF = (size_t)MAXB * (NW + 1) * sizeof(int);

    const size_t part_full = (size_t)2 * MAXB * DSTB * sizeof(float); // 2*nbins partials
    const size_t need_full = 2 * E4 + WOFF + SMALL + 512;   // overlay inside s1
    const size_t part_t2   = (size_t)MAXB * DSTB * sizeof(float);
    const size_t need_t2   = E4 + 4 * NBP + part_t2 + SMALL + 512;
    (void)part_full;

    const bool shape_ok = (nbins <= MAXB) && (n_nodes <= (1 << 20));

    if (shape_ok && ws_size >= need_full) {
        // ---- FULL path ----
        char* ws = (char*)d_ws;
        uint32_t* s2 = (uint32_t*)ws;                      ws += E4;
        char* ov = ws;                                     // overlay region (s1)
        uint32_t* s1 = (uint32_t*)ov;                      ws += E4;
        float* xw0 = (float*)(ov);
        float* s0  = (float*)(ov + NBP);
        float* h_a = (float*)(ov + 2 * NBP);
        float* h_b = (float*)(ov + 3 * NBP);
        float* partial = (float*)(ov + 4 * NBP);           // 2*nbins*32KB <= 16MB
        int* woffs  = (int*)ws;                            ws += WOFF;
        int* counts = (int*)ws;                            ws += MAXB * sizeof(int);
        int* offs   = (int*)ws;                            ws += (MAXB + 1) * sizeof(int);
        int* cursor = (int*)ws;                            ws += MAXB * sizeof(int);
        float* hg   = (float*)ws;

        hipMemsetAsync(counts, 0, MAXB * sizeof(int), stream);
        hipMemsetAsync(hg, 0, NGRAPHS * sizeof(float), stream);

        count_bins2<<<2048, TB, 0, stream>>>(src, dst, n_edges, nbins, counts);
        scan_offsets<<<1, MAXB, 0, stream>>>(counts, nbins, offs, cursor);
        place1<<<PGRID, TB_P, 0, stream>>>(src, dst, n_edges, nbins, cursor, s1);
        window_sort<<<nbins, TB2, 0, stream>>>(s1, offs, s2, woffs);
        // s1 dead: overlay node arrays + partials
        node_init<<<node_blocks, TB, 0, stream>>>((const float4*)x, W0n, W0s, xw0, s0, n_nodes);

        window_agg<<<2 * nbins, TB_A, 0, stream>>>(s2, woffs, xw0, partial);
        reduce_l0<<<nbd, 1024, 0, stream>>>(partial, 4, s0, b0, h_a, n_nodes);

        window_agg<<<2 * nbins, TB_A, 0, stream>>>(s2, woffs, h_a, partial);
        reduce_lk<<<nbd, 1024, 0, stream>>>(partial, 4, h_a, Wkn, bk, Wks, 0, h_b, n_nodes);

        window_agg<<<2 * nbins, TB_A, 0, stream>>>(s2, woffs, h_b, partial);
        reduce_lk<<<nbd, 1024, 0, stream>>>(partial, 4, h_b, Wkn, bk, Wks, 1, h_a, n_nodes);

        window_agg<<<2 * nbins, TB_A, 0, stream>>>(s2, woffs, h_a, partial);
        reduce_last<<<nbd, 1024, 0, stream>>>(partial, 4, h_a, graphids, Wkn, bk, Wks, 2, hg, n_nodes);

        head<<<1, TB, 0, stream>>>(hg, fc1_w, fc1_b, out_w, out_b, out);
    } else if (shape_ok && ws_size >= need_t2) {
        // ---- TIER2: gather path on pass1 output ----
        char* ws = (char*)d_ws;
        uint32_t* s1 = (uint32_t*)ws;                      ws += E4;
        float* xw0 = (float*)ws;                           ws += NBP;
        float* s0  = (float*)ws;                           ws += NBP;
        float* h_a = (float*)ws;                           ws += NBP;
        float* h_b = (float*)ws;                           ws += NBP;
        float* partial = (float*)ws;                       ws += part_t2;
        int* counts = (int*)ws;                            ws += MAXB * sizeof(int);
        int* offs   = (int*)ws;                            ws += (MAXB + 1) * sizeof(int);
        int* cursor = (int*)ws;                            ws += MAXB * sizeof(int);
        float* hg   = (float*)ws;

        hipMemsetAsync(counts, 0, MAXB * sizeof(int), stream);
        hipMemsetAsync(hg, 0, NGRAPHS * sizeof(float), stream);

        count_bins2<<<2048, TB, 0, stream>>>(src, dst, n_edges, nbins, counts);
        scan_offsets<<<1, MAXB, 0, stream>>>(counts, nbins, offs, cursor);
        place1<<<PGRID, TB_P, 0, stream>>>(src, dst, n_edges, nbins, cursor, s1);
        node_init<<<node_blocks, TB, 0, stream>>>((const float4*)x, W0n, W0s, xw0, s0, n_nodes);

        plain_agg<<<nbins, TB_A, 0, stream>>>(s1, offs, xw0, partial);
        reduce_l0<<<nbd, 1024, 0, stream>>>(partial, 2, s0, b0, h_a, n_nodes);
        plain_agg<<<nbins, TB_A, 0, stream>>>(s1, offs, h_a, partial);
        reduce_lk<<<nbd, 1024, 0, stream>>>(partial, 2, h_a, Wkn, bk, Wks, 0, h_b, n_nodes);
        plain_agg<<<nbins, TB_A, 0, stream>>>(s1, offs, h_b, partial);
        reduce_lk<<<nbd, 1024, 0, stream>>>(partial, 2, h_b, Wkn, bk, Wks, 1, h_a, n_nodes);
        plain_agg<<<nbins, TB_A, 0, stream>>>(s1, offs, h_a, partial);
        reduce_last<<<nbd, 1024, 0, stream>>>(partial, 2, h_a, graphids, Wkn, bk, Wks, 2, hg, n_nodes);

        head<<<1, TB, 0, stream>>>(hg, fc1_w, fc1_b, out_w, out_b, out);
    } else {
        // ---- TIER3: global atomics ----
        const size_t NB = (size_t)n_nodes * sizeof(float);
        char* ws   = (char*)d_ws;
        float* agg = (float*)(ws);
        float* h   = (float*)(ws + NB);
        float* xw0 = (float*)(ws + 2 * NB);
        float* s0  = (float*)(ws + 3 * NB);
        float* hg  = (float*)(ws + 4 * NB);
        const int nquads = n_edges >> 2;
        const int edge_blocks = (nquads + TB - 1) / TB;

        hipMemsetAsync(agg, 0, NB, stream);
        hipMemsetAsync(hg, 0, NGRAPHS * sizeof(float), stream);

        node_init<<<node_blocks, TB, 0, stream>>>((const float4*)x, W0n, W0s, xw0, s0, n_nodes);
        edge_scatter<<<edge_blocks, TB, 0, stream>>>((const int4*)src, (const int4*)dst, xw0, agg, nquads);
        node_l0<<<node_blocks, TB, 0, stream>>>(agg, s0, b0, h, n_nodes);
        for (int li = 0; li < 2; ++li) {
            edge_scatter<<<edge_blocks, TB, 0, stream>>>((const int4*)src, (const int4*)dst, h, agg, nquads);
            node_lk<<<node_blocks, TB, 0, stream>>>(agg, h, Wkn, bk, Wks, li, n_nodes);
        }
        edge_scatter<<<edge_blocks, TB, 0, stream>>>((const int4*)src, (const int4*)dst, h, agg, nquads);
        node_l3_readout<<<node_blocks, TB, 0, stream>>>(agg, h, graphids, Wkn, bk, Wks, hg, n_nodes);
        head<<<1, TB, 0, stream>>>(hg, fc1_w, fc1_b, out_w, out_b, out);
    }
}

// Round 7
// 721.747 us; speedup vs baseline: 1.1824x; 1.1824x over previous
//
#include <hip/hip_runtime.h>
#include <stdint.h>

// GCN, DIM=1. Build: pass1 bins edges by (32K-node dst-bucket x 128K src-block)
// [248 bins; rec = dstloc15<<17 | srcloc17]; pass2 sorts each bin by 256-src
// window (9-bit LDS counting sort). Layers: barrier-free linear scan per bin,
// gathers hit <=16 unique lines per wave-instr (TCP-coalesced, L1-hot),
// LDS atomics into a 128KB accumulator; streaming reduce fuses node update.

static constexpr int NGRAPHS  = 256;
static constexpr int TB       = 256;
static constexpr int TB_P     = 512;    // place block
static constexpr int PGRID    = 256;    // place grid (1 block/CU)
static constexpr int TB2      = 1024;   // window_sort block
static constexpr int TB_A     = 1024;   // agg block
static constexpr int TB_R     = 512;    // reduce block
static constexpr int DSTB_LOG = 15;
static constexpr int DSTB     = 1 << DSTB_LOG;   // 32768 dst nodes per bucket
static constexpr int NSB_LOG  = 3;               // 8 src blocks
static constexpr int SRCB_LOG = 17;              // 128K srcs per block
static constexpr uint32_t SRCMASK = (1u << SRCB_LOG) - 1;
static constexpr int MAXB     = 256;             // max bins
static constexpr int WLOG2    = 8;               // 256-src windows
static constexpr int NW2      = 512;             // windows per src-block (2^17/2^8)
static constexpr int TILE2    = 4096;            // pass2 staging tile

// ---------------- common ----------------

__global__ void node_init(const float4* __restrict__ x,
                          const float* __restrict__ W0n,
                          const float* __restrict__ W0s,
                          float* __restrict__ xw0,
                          float* __restrict__ s0,
                          int n_nodes) {
    int n = blockIdx.x * blockDim.x + threadIdx.x;
    if (n >= n_nodes) return;
    float4 a = x[2 * n];
    float4 b = x[2 * n + 1];
    float xn = a.x * W0n[0] + a.y * W0n[1] + a.z * W0n[2] + a.w * W0n[3] +
               b.x * W0n[4] + b.y * W0n[5] + b.z * W0n[6] + b.w * W0n[7];
    float xs = a.x * W0s[0] + a.y * W0s[1] + a.z * W0s[2] + a.w * W0s[3] +
               b.x * W0s[4] + b.y * W0s[5] + b.z * W0s[6] + b.w * W0s[7];
    xw0[n] = xn;
    s0[n] = xs;
}

__global__ void head(const float* __restrict__ hg,
                     const float* __restrict__ fc1_w,
                     const float* __restrict__ fc1_b,
                     const float* __restrict__ out_w,
                     const float* __restrict__ out_b,
                     float* __restrict__ out) {
    int gph = threadIdx.x;
    if (gph >= NGRAPHS) return;
    float hv = hg[gph];
    float o0 = out_b[0], o1 = out_b[1], o2 = out_b[2], o3 = out_b[3];
#pragma unroll
    for (int j = 0; j < 8; ++j) {
        float z = (hv * fc1_w[j] + fc1_b[j]) * 1000.0f;
        float sg = 1.0f / (1.0f + expf(-z));
        o0 += sg * out_w[j * 4 + 0];
        o1 += sg * out_w[j * 4 + 1];
        o2 += sg * out_w[j * 4 + 2];
        o3 += sg * out_w[j * 4 + 3];
    }
    o0 = fmaxf(o0, 0.0f); o1 = fmaxf(o1, 0.0f);
    o2 = fmaxf(o2, 0.0f); o3 = fmaxf(o3, 0.0f);
    float m = fmaxf(fmaxf(o0, o1), fmaxf(o2, o3));
    float s = expf(o0 - m) + expf(o1 - m) + expf(o2 - m) + expf(o3 - m);
    float l = logf(s);
    out[gph * 4 + 0] = o0 - m - l;
    out[gph * 4 + 1] = o1 - m - l;
    out[gph * 4 + 2] = o2 - m - l;
    out[gph * 4 + 3] = o3 - m - l;
}

__device__ __forceinline__ int bin1_of(int d, int s) {
    return ((d >> DSTB_LOG) << NSB_LOG) | ((unsigned)s >> SRCB_LOG);
}
__device__ __forceinline__ uint32_t rec_of(int d, int s) {
    return ((uint32_t)(d & (DSTB - 1)) << SRCB_LOG) | ((uint32_t)s & SRCMASK);
}

// ---------------- build: count + scan + pass1 ----------------

__global__ void count_bins2(const int* __restrict__ src,
                            const int* __restrict__ dst,
                            int n_edges, int nbins,
                            int* __restrict__ counts) {
    __shared__ int hist[MAXB];
    for (int i = threadIdx.x; i < MAXB; i += blockDim.x) hist[i] = 0;
    __syncthreads();
    const int4* s4 = (const int4*)src;
    const int4* d4 = (const int4*)dst;
    int nq = n_edges >> 2;
    int g = blockIdx.x * blockDim.x + threadIdx.x;
    int stride = gridDim.x * blockDim.x;
    for (int q = g; q < nq; q += stride) {
        int4 d = d4[q]; int4 s = s4[q];
        atomicAdd(&hist[bin1_of(d.x, s.x)], 1);
        atomicAdd(&hist[bin1_of(d.y, s.y)], 1);
        atomicAdd(&hist[bin1_of(d.z, s.z)], 1);
        atomicAdd(&hist[bin1_of(d.w, s.w)], 1);
    }
    if (blockIdx.x == 0) {
        for (int e = (nq << 2) + threadIdx.x; e < n_edges; e += blockDim.x)
            atomicAdd(&hist[bin1_of(dst[e], src[e])], 1);
    }
    __syncthreads();
    for (int i = threadIdx.x; i < nbins; i += blockDim.x)
        if (hist[i]) atomicAdd(&counts[i], hist[i]);
}

__global__ void scan_offsets(const int* __restrict__ counts, int nbins,
                             int* __restrict__ offs, int* __restrict__ cursor) {
    __shared__ int lds[MAXB];
    int i = threadIdx.x;
    int c = (i < nbins) ? counts[i] : 0;
    lds[i] = c;
    __syncthreads();
    for (int off = 1; off < MAXB; off <<= 1) {
        int v = (i >= off) ? lds[i - off] : 0;
        __syncthreads();
        lds[i] += v;
        __syncthreads();
    }
    int excl = lds[i] - c;
    offs[i] = excl;                // for i >= nbins this equals total
    if (i < nbins) cursor[i] = excl;
    if (i == MAXB - 1) offs[MAXB] = lds[MAXB - 1];
}

__global__ void place1(const int* __restrict__ src,
                       const int* __restrict__ dst,
                       int n_edges, int nbins,
                       int* __restrict__ cursor,
                       uint32_t* __restrict__ sorted) {
    __shared__ int hist[MAXB];
    for (int i = threadIdx.x; i < MAXB; i += blockDim.x) hist[i] = 0;
    __syncthreads();

    const int nq = n_edges >> 2;
    const int per = (nq + gridDim.x - 1) / gridDim.x;
    const int b0 = blockIdx.x * per;
    const int b1 = min(b0 + per, nq);
    const bool last = (blockIdx.x == gridDim.x - 1);
    const int tail = nq << 2;

    const int4* s4 = (const int4*)src;
    const int4* d4 = (const int4*)dst;

    for (int q = b0 + threadIdx.x; q < b1; q += blockDim.x) {
        int4 d = d4[q]; int4 s = s4[q];
        atomicAdd(&hist[bin1_of(d.x, s.x)], 1);
        atomicAdd(&hist[bin1_of(d.y, s.y)], 1);
        atomicAdd(&hist[bin1_of(d.z, s.z)], 1);
        atomicAdd(&hist[bin1_of(d.w, s.w)], 1);
    }
    if (last) {
        for (int e = tail + threadIdx.x; e < n_edges; e += blockDim.x)
            atomicAdd(&hist[bin1_of(dst[e], src[e])], 1);
    }
    __syncthreads();
    for (int b = threadIdx.x; b < nbins; b += blockDim.x) {
        int h = hist[b];
        hist[b] = h ? atomicAdd(&cursor[b], h) : 0;
    }
    __syncthreads();
    for (int q = b0 + threadIdx.x; q < b1; q += blockDim.x) {
        int4 d = d4[q]; int4 s = s4[q];
        int p0 = atomicAdd(&hist[bin1_of(d.x, s.x)], 1);
        int p1 = atomicAdd(&hist[bin1_of(d.y, s.y)], 1);
        int p2 = atomicAdd(&hist[bin1_of(d.z, s.z)], 1);
        int p3 = atomicAdd(&hist[bin1_of(d.w, s.w)], 1);
        sorted[p0] = rec_of(d.x, s.x);
        sorted[p1] = rec_of(d.y, s.y);
        sorted[p2] = rec_of(d.z, s.z);
        sorted[p3] = rec_of(d.w, s.w);
    }
    if (last) {
        for (int e = tail + threadIdx.x; e < n_edges; e += blockDim.x) {
            int pos = atomicAdd(&hist[bin1_of(dst[e], src[e])], 1);
            sorted[pos] = rec_of(dst[e], src[e]);
        }
    }
}

// ---------------- pass2: per-bin 256-src window sort ----------------

__global__ __launch_bounds__(TB2) void window_sort(const uint32_t* __restrict__ s1,
                                                   const int* __restrict__ offs,
                                                   uint32_t* __restrict__ s2) {
    __shared__ int whist[NW2];
    __shared__ int wcur[NW2];
    __shared__ int thist[NW2];
    __shared__ int tincl[NW2];
    __shared__ int tcur[NW2];
    __shared__ uint32_t stg[TILE2];
    __shared__ uint16_t bid[TILE2];
    const int bin = blockIdx.x;
    const int tid = threadIdx.x;
    const int beg = offs[bin], end = offs[bin + 1];

    if (tid < NW2) whist[tid] = 0;
    __syncthreads();
    for (int e = beg + tid; e < end; e += TB2)
        atomicAdd(&whist[(s1[e] >> WLOG2) & (NW2 - 1)], 1);
    __syncthreads();
    if (tid < NW2) wcur[tid] = whist[tid];
    __syncthreads();
    for (int off = 1; off < NW2; off <<= 1) {
        int v = (tid < NW2 && tid >= off) ? wcur[tid - off] : 0;
        __syncthreads();
        if (tid < NW2) wcur[tid] += v;
        __syncthreads();
    }
    if (tid < NW2) wcur[tid] -= whist[tid];   // exclusive start
    __syncthreads();

    for (int tb = beg; tb < end; tb += TILE2) {
        const int cnt = min(TILE2, end - tb);
        if (tid < NW2) thist[tid] = 0;
        __syncthreads();
        uint32_t r[TILE2 / TB2];
        int bn[TILE2 / TB2];
#pragma unroll
        for (int k = 0; k < TILE2 / TB2; ++k) {
            int e = tb + k * TB2 + tid;
            if (e < end) {
                r[k] = s1[e];
                bn[k] = (r[k] >> WLOG2) & (NW2 - 1);
                atomicAdd(&thist[bn[k]], 1);
            } else bn[k] = -1;
        }
        __syncthreads();
        if (tid < NW2) tincl[tid] = thist[tid];
        __syncthreads();
        for (int off = 1; off < NW2; off <<= 1) {
            int v = (tid < NW2 && tid >= off) ? tincl[tid - off] : 0;
            __syncthreads();
            if (tid < NW2) tincl[tid] += v;
            __syncthreads();
        }
        if (tid < NW2) tcur[tid] = tincl[tid] - thist[tid];
        __syncthreads();
#pragma unroll
        for (int k = 0; k < TILE2 / TB2; ++k) {
            if (bn[k] >= 0) {
                int p = atomicAdd(&tcur[bn[k]], 1);
                stg[p] = r[k];
                bid[p] = (uint16_t)bn[k];
            }
        }
        __syncthreads();
        for (int i = tid; i < cnt; i += TB2) {
            int w = bid[i];
            int es = tincl[w] - thist[w];
            s2[beg + wcur[w] + (i - es)] = stg[i];
        }
        __syncthreads();
        if (tid < NW2) wcur[tid] += thist[tid];
        __syncthreads();
    }
}

// ---------------- per-layer aggregation: barrier-free, L1-local gather ----------------

__global__ __launch_bounds__(TB_A) void win_gather_agg(const uint32_t* __restrict__ s2,
                                                       const int* __restrict__ offs,
                                                       const float* __restrict__ gsrc,
                                                       float* __restrict__ partial) {
    __shared__ float acc[DSTB];   // 128 KB
    const int bin = blockIdx.x;
    const int tid = threadIdx.x;
    for (int i = tid; i < DSTB; i += TB_A) acc[i] = 0.0f;
    __syncthreads();
    const float* hs = gsrc + ((size_t)(bin & ((1 << NSB_LOG) - 1)) << SRCB_LOG);
    const int beg = offs[bin], end = offs[bin + 1];
    int e = beg + tid;
    for (; e + 3 * TB_A < end; e += 4 * TB_A) {
        uint32_t r0 = s2[e];
        uint32_t r1 = s2[e + TB_A];
        uint32_t r2 = s2[e + 2 * TB_A];
        uint32_t r3 = s2[e + 3 * TB_A];
        float v0 = hs[r0 & SRCMASK];
        float v1 = hs[r1 & SRCMASK];
        float v2 = hs[r2 & SRCMASK];
        float v3 = hs[r3 & SRCMASK];
        atomicAdd(&acc[r0 >> SRCB_LOG], v0);
        atomicAdd(&acc[r1 >> SRCB_LOG], v1);
        atomicAdd(&acc[r2 >> SRCB_LOG], v2);
        atomicAdd(&acc[r3 >> SRCB_LOG], v3);
    }
    for (; e < end; e += TB_A) {
        uint32_t r = s2[e];
        atomicAdd(&acc[r >> SRCB_LOG], hs[r & SRCMASK]);
    }
    __syncthreads();
    float* o = partial + (size_t)bin * DSTB;
    for (int i = tid; i < DSTB; i += TB_A) o[i] = acc[i];
}

// ---------------- reduce partials + fused node update ----------------
// grid = nbd*8; block handles a 4096-node slice of one dst bucket.

__global__ void reduce_l0(const float* __restrict__ partial,
                          const float* __restrict__ s0,
                          const float* __restrict__ b0,
                          float* __restrict__ h_out, int n_nodes) {
    const int k = blockIdx.x >> 3;
    const int sl = blockIdx.x & 7;
    const int base = (k << DSTB_LOG) + (sl << 12);
    const int nloc = min(4096, n_nodes - base);
    if (nloc <= 0) return;
    const float* p = partial + ((size_t)k << (NSB_LOG + DSTB_LOG)) + (sl << 12);
    float bb = b0[0];
    for (int i = threadIdx.x; i < nloc; i += blockDim.x) {
        float v = 0.0f;
#pragma unroll
        for (int j = 0; j < 8; ++j) v += p[(size_t)j * DSTB + i];
        h_out[base + i] = fmaxf(v + bb + s0[base + i], 0.0f);
    }
}

__global__ void reduce_lk(const float* __restrict__ partial,
                          const float* __restrict__ h_in,
                          const float* __restrict__ Wkn,
                          const float* __restrict__ bk,
                          const float* __restrict__ Wks,
                          int li, float* __restrict__ h_out, int n_nodes) {
    const int k = blockIdx.x >> 3;
    const int sl = blockIdx.x & 7;
    const int base = (k << DSTB_LOG) + (sl << 12);
    const int nloc = min(4096, n_nodes - base);
    if (nloc <= 0) return;
    const float* p = partial + ((size_t)k << (NSB_LOG + DSTB_LOG)) + (sl << 12);
    float wn = Wkn[li], bb = bk[li], ws = Wks[li];
    for (int i = threadIdx.x; i < nloc; i += blockDim.x) {
        float v = 0.0f;
#pragma unroll
        for (int j = 0; j < 8; ++j) v += p[(size_t)j * DSTB + i];
        h_out[base + i] = fmaxf(wn * v + bb + ws * h_in[base + i], 0.0f);
    }
}

__global__ void reduce_last(const float* __restrict__ partial,
                            const float* __restrict__ h_in,
                            const int* __restrict__ graph_ids,
                            const float* __restrict__ Wkn,
                            const float* __restrict__ bk,
                            const float* __restrict__ Wks,
                            int li, float* __restrict__ hg, int n_nodes) {
    const int k = blockIdx.x >> 3;
    const int sl = blockIdx.x & 7;
    const int base = (k << DSTB_LOG) + (sl << 12);
    if (base >= n_nodes) return;
    const int nloc = min(4096, n_nodes - base);
    const float* p = partial + ((size_t)k << (NSB_LOG + DSTB_LOG)) + (sl << 12);
    float wn = Wkn[li], bb = bk[li], ws = Wks[li];
    for (int i = threadIdx.x; i < 4096; i += blockDim.x) {  // uniform bound
        float val = 0.0f;
        int g = -1;
        if (i < nloc) {
            float v = 0.0f;
#pragma unroll
            for (int j = 0; j < 8; ++j) v += p[(size_t)j * DSTB + i];
            int n = base + i;
            val = fmaxf(wn * v + bb + ws * h_in[n], 0.0f);
            g = graph_ids[n];
        }
        int g0 = __shfl(g, 0);
        unsigned long long same = __ballot(g == g0);
        if (same == ~0ULL) {
            for (int o = 32; o > 0; o >>= 1) val += __shfl_down(val, o);
            if ((threadIdx.x & 63) == 0 && g >= 0) atomicAdd(&hg[g], val);
        } else if (g >= 0) {
            atomicAdd(&hg[g], val);
        }
    }
}

// ---------------- fallback: global atomics ----------------

__global__ void edge_scatter(const int4* __restrict__ src4,
                             const int4* __restrict__ dst4,
                             const float* __restrict__ val,
                             float* __restrict__ agg, int nquads) {
    int t = blockIdx.x * blockDim.x + threadIdx.x;
    if (t >= nquads) return;
    int4 s = src4[t]; int4 d = dst4[t];
    atomicAdd(&agg[d.x], val[s.x]);
    atomicAdd(&agg[d.y], val[s.y]);
    atomicAdd(&agg[d.z], val[s.z]);
    atomicAdd(&agg[d.w], val[s.w]);
}

__global__ void node_l0(float* __restrict__ agg, const float* __restrict__ s0,
                        const float* __restrict__ b0, float* __restrict__ h, int n_nodes) {
    int n = blockIdx.x * blockDim.x + threadIdx.x;
    if (n >= n_nodes) return;
    h[n] = fmaxf(agg[n] + b0[0] + s0[n], 0.0f);
    agg[n] = 0.0f;
}

__global__ void node_lk(float* __restrict__ agg, float* __restrict__ h,
                        const float* __restrict__ Wkn, const float* __restrict__ bk,
                        const float* __restrict__ Wks, int li, int n_nodes) {
    int n = blockIdx.x * blockDim.x + threadIdx.x;
    if (n >= n_nodes) return;
    float v = Wkn[li] * agg[n] + bk[li] + Wks[li] * h[n];
    h[n] = fmaxf(v, 0.0f);
    agg[n] = 0.0f;
}

__global__ void node_l3_readout(const float* __restrict__ agg, const float* __restrict__ h,
                                const int* __restrict__ graph_ids,
                                const float* __restrict__ Wkn, const float* __restrict__ bk,
                                const float* __restrict__ Wks, float* __restrict__ hg,
                                int n_nodes) {
    int n = blockIdx.x * blockDim.x + threadIdx.x;
    float val = 0.0f;
    int g = -1;
    if (n < n_nodes) {
        val = fmaxf(Wkn[2] * agg[n] + bk[2] + Wks[2] * h[n], 0.0f);
        g = graph_ids[n];
    }
    int g0 = __shfl(g, 0);
    unsigned long long same = __ballot(g == g0);
    if (same == ~0ULL) {
        for (int o = 32; o > 0; o >>= 1) val += __shfl_down(val, o);
        if ((threadIdx.x & 63) == 0 && g >= 0) atomicAdd(&hg[g], val);
    } else if (g >= 0) {
        atomicAdd(&hg[g], val);
    }
}

// ---------------- launch ----------------

extern "C" void kernel_launch(void* const* d_in, const int* in_sizes, int n_in,
                              void* d_out, int out_size, void* d_ws, size_t ws_size,
                              hipStream_t stream) {
    const float* x        = (const float*)d_in[0];
    const int*   src      = (const int*)d_in[1];
    const int*   dst      = (const int*)d_in[2];
    const int*   graphids = (const int*)d_in[3];
    const float* W0n   = (const float*)d_in[5];
    const float* b0    = (const float*)d_in[6];
    const float* W0s   = (const float*)d_in[7];
    const float* Wkn   = (const float*)d_in[8];
    const float* bk    = (const float*)d_in[9];
    const float* Wks   = (const float*)d_in[10];
    const float* fc1_w = (const float*)d_in[11];
    const float* fc1_b = (const float*)d_in[12];
    const float* out_w = (const float*)d_in[13];
    const float* out_b = (const float*)d_in[14];
    float* out = (float*)d_out;

    const int n_nodes = in_sizes[0] / 8;
    const int n_edges = in_sizes[1];
    const int nbd     = (n_nodes + DSTB - 1) >> DSTB_LOG;          // dst buckets
    const int nbins   = nbd << NSB_LOG;                            // x 8 src blocks
    const int node_blocks = (n_nodes + TB - 1) / TB;

    const size_t E4    = (size_t)n_edges * 4;
    const size_t NBP   = (size_t)(1 << 20) * sizeof(float);        // padded node array (4MB)
    const size_t SMALL = (MAXB + (MAXB + 1) + MAXB + NGRAPHS) * sizeof(int);
    const size_t part_bytes = (size_t)nbins * DSTB * sizeof(float);
    const size_t ov_bytes   = (4 * NBP + part_bytes > E4) ? (4 * NBP + part_bytes) : E4;
    const size_t need_full  = E4 + ov_bytes + SMALL + 512;

    const bool shape_ok = (nbins <= MAXB) && (n_nodes <= (1 << 20)) && (n_edges >= 4);

    if (shape_ok && ws_size >= need_full) {
        // ---- FULL path ----
        char* ws = (char*)d_ws;
        uint32_t* s2 = (uint32_t*)ws;                      ws += E4;
        char* ov = ws;                                     ws += ov_bytes;
        uint32_t* s1 = (uint32_t*)ov;                      // build-time alias
        float* xw0 = (float*)(ov);
        float* s0  = (float*)(ov + NBP);
        float* h_a = (float*)(ov + 2 * NBP);
        float* h_b = (float*)(ov + 3 * NBP);
        float* partial = (float*)(ov + 4 * NBP);
        int* counts = (int*)ws;                            ws += MAXB * sizeof(int);
        int* offs   = (int*)ws;                            ws += (MAXB + 1) * sizeof(int);
        int* cursor = (int*)ws;                            ws += MAXB * sizeof(int);
        float* hg   = (float*)ws;

        hipMemsetAsync(counts, 0, MAXB * sizeof(int), stream);
        hipMemsetAsync(hg, 0, NGRAPHS * sizeof(float), stream);

        count_bins2<<<2048, TB, 0, stream>>>(src, dst, n_edges, nbins, counts);
        scan_offsets<<<1, MAXB, 0, stream>>>(counts, nbins, offs, cursor);
        place1<<<PGRID, TB_P, 0, stream>>>(src, dst, n_edges, nbins, cursor, s1);
        window_sort<<<nbins, TB2, 0, stream>>>(s1, offs, s2);
        // s1 dead: overlay node arrays + partials
        node_init<<<node_blocks, TB, 0, stream>>>((const float4*)x, W0n, W0s, xw0, s0, n_nodes);

        const int rgrid = nbd << 3;
        win_gather_agg<<<nbins, TB_A, 0, stream>>>(s2, offs, xw0, partial);
        reduce_l0<<<rgrid, TB_R, 0, stream>>>(partial, s0, b0, h_a, n_nodes);

        win_gather_agg<<<nbins, TB_A, 0, stream>>>(s2, offs, h_a, partial);
        reduce_lk<<<rgrid, TB_R, 0, stream>>>(partial, h_a, Wkn, bk, Wks, 0, h_b, n_nodes);

        win_gather_agg<<<nbins, TB_A, 0, stream>>>(s2, offs, h_b, partial);
        reduce_lk<<<rgrid, TB_R, 0, stream>>>(partial, h_b, Wkn, bk, Wks, 1, h_a, n_nodes);

        win_gather_agg<<<nbins, TB_A, 0, stream>>>(s2, offs, h_a, partial);
        reduce_last<<<rgrid, TB_R, 0, stream>>>(partial, h_a, graphids, Wkn, bk, Wks, 2, hg, n_nodes);

        head<<<1, TB, 0, stream>>>(hg, fc1_w, fc1_b, out_w, out_b, out);
    } else {
        // ---- fallback: global atomics ----
        const size_t NB = (size_t)n_nodes * sizeof(float);
        char* ws   = (char*)d_ws;
        float* agg = (float*)(ws);
        float* h   = (float*)(ws + NB);
        float* xw0 = (float*)(ws + 2 * NB);
        float* s0  = (float*)(ws + 3 * NB);
        float* hg  = (float*)(ws + 4 * NB);
        const int nquads = n_edges >> 2;
        const int edge_blocks = (nquads + TB - 1) / TB;

        hipMemsetAsync(agg, 0, NB, stream);
        hipMemsetAsync(hg, 0, NGRAPHS * sizeof(float), stream);

        node_init<<<node_blocks, TB, 0, stream>>>((const float4*)x, W0n, W0s, xw0, s0, n_nodes);
        edge_scatter<<<edge_blocks, TB, 0, stream>>>((const int4*)src, (const int4*)dst, xw0, agg, nquads);
        node_l0<<<node_blocks, TB, 0, stream>>>(agg, s0, b0, h, n_nodes);
        for (int li = 0; li < 2; ++li) {
            edge_scatter<<<edge_blocks, TB, 0, stream>>>((const int4*)src, (const int4*)dst, h, agg, nquads);
            node_lk<<<node_blocks, TB, 0, stream>>>(agg, h, Wkn, bk, Wks, li, n_nodes);
        }
        edge_scatter<<<edge_blocks, TB, 0, stream>>>((const int4*)src, (const int4*)dst, h, agg, nquads);
        node_l3_readout<<<node_blocks, TB, 0, stream>>>(agg, h, graphids, Wkn, bk, Wks, hg, n_nodes);
        head<<<1, TB, 0, stream>>>(hg, fc1_w, fc1_b, out_w, out_b, out);
    }
}